// Round 13
// baseline (22.661 us; speedup 1.0000x reference)
//
#include <hip/hip_runtime.h>
#include <cstdint>
#include <cstddef>

// BAP: out0[b,m,c] = (1/HW) * sum_k feat[b,c,k] * sigmoid(raw[b,m,k])
//      out1[b,m,k] = sigmoid(raw[b,m,k])
// B=16, C=1024, M=32, K=H*W=1024.
// R12: R11 (22.6us) kept the per-stage __syncthreads vmcnt(0) drain.
// Fix = T4 counted vmcnt on the att-free structure: 4-deep feat ring,
// raw s_barrier, vmcnt(16/8/0) retiring one (af+stage) pair per iter;
// af loads pinned in the vmcnt FIFO via inline-asm global_load_dwordx4.

#define BB 16
#define CC 1024
#define MM 32
#define HW 1024

#define TCR 32               // c-rows per block
#define TKF 128              // feat k per stage -> 32 x 16B slots per row
#define NSTF (HW / TKF)      // 8 stages
#define ND 4                 // ring depth

typedef __attribute__((ext_vector_type(4))) float f32x4;
typedef __attribute__((ext_vector_type(8))) float f32x8;
typedef __attribute__((ext_vector_type(8))) short s16x8;

__device__ inline short bf16rne(float x)
{
    uint32_t u = __builtin_bit_cast(uint32_t, x);
    u = (u + 0x7FFFu + ((u >> 16) & 1u)) >> 16;
    return (short)u;
}

__device__ inline s16x8 cvt8(f32x4 lo, f32x4 hi)
{
    s16x8 r;
#pragma unroll
    for (int j = 0; j < 4; ++j) {
        r[j]     = bf16rne(lo[j]);
        r[4 + j] = bf16rne(hi[j]);
    }
    return r;
}

// async global->LDS, 16B/lane, wave-uniform LDS base (HW: base + lane*16)
__device__ inline void gld_lds16(const void* g, void* l)
{
    __builtin_amdgcn_global_load_lds(
        (const __attribute__((address_space(1))) void*)g,
        (__attribute__((address_space(3))) void*)l, 16, 0, 0);
}

// ---------------- kernel 1: sigmoid + linear bf16 att to ws ----------------
__global__ __launch_bounds__(256) void sigmoid_kernel(
    const float* __restrict__ raw, float* __restrict__ out1,
    unsigned short* __restrict__ ws)
{
    int g = blockIdx.x * 256 + threadIdx.x;      // 0..65535, 8 elems each
    f32x8 v = reinterpret_cast<const f32x8*>(raw)[g];
    f32x8 s;
    s16x8 h;
#pragma unroll
    for (int j = 0; j < 8; ++j) {
        s[j] = 1.0f / (1.0f + __expf(-v[j]));
        h[j] = bf16rne(s[j]);
    }
    reinterpret_cast<f32x8*>(out1)[g] = s;
    reinterpret_cast<s16x8*>(ws)[g] = h;         // linear [b][m][k] bf16
}

// ---------------- kernel 2: MFMA contraction, counted-vmcnt ring ----------
// Grid 512 = 32 c-tiles x 16 b (b = low 4 bits -> same-b blocks share XCD).
// 256 threads = 4 waves; wave w = (mt=w>>1, c2=w&1) -> one 16x16 acc.
// feat ring fsh[ND=4][32][128] (64 KB -> 2 blocks/CU), XOR-slot swizzle via
// pre-swizzled gload_lds source (rule #21). A-fragments: inline-asm
// global_load_dwordx4 from L2-hot ws, 3 stages ahead, af[4][4] regs.
// Per iter: vmcnt(16) retires pair s (4 af + 4 stage ops); pairs s+1,s+2
// stay in flight across the barrier (T4 — never drain to 0 mid-loop).
__global__ __launch_bounds__(256) void bap_mfma(
    const float* __restrict__ feat,          // [B][C][HW] fp32
    const unsigned short* __restrict__ ws,   // [B][32][1024] bf16 linear
    float* __restrict__ out0)                // [B][M][C]
{
    __shared__ float fsh[ND][TCR][TKF];      // 64 KB

    const int t  = threadIdx.x;
    const int w  = t >> 6;                   // wave 0..3
    const int l  = t & 63;
    const int b  = blockIdx.x & 15;
    const int ct = blockIdx.x >> 4;          // 0..31
    const int cbase = ct * TCR;

    const int lrow  = l >> 5;                // 0..1 (row within 2-row chunk)
    const int lslot = l & 31;                // 16B slot within 512B row

    const float* fbase = feat + (size_t)(b * CC + cbase) * HW;

    // feat stage s -> ring buf s&3: 4 gld_lds16/lane, 2 rows each (16 KB)
    auto stage = [&](int s) {
        const int nb = s & (ND - 1);
        const int k0 = s * TKF;
#pragma unroll
        for (int i = 0; i < 4; ++i) {
            int r0  = w * 8 + i * 2;                  // wave-uniform
            int row = r0 + lrow;
            int sg  = lslot ^ (row & 15);             // source-side swizzle
            gld_lds16(fbase + (size_t)row * HW + k0 + sg * 4,
                      &fsh[nb][r0][0]);
        }
    };

    // MFMA geometry (variant 0, R7/R8/R10-proven)
    const int r  = l & 15;
    const int q  = l >> 4;
    const int mt = w >> 1;                   // 0..1
    const int c2 = w & 1;                    // 0..1
    const int arow = mt * 16 + r;
    const int brow = c2 * 16 + r;            // brow & 15 == r
    const s16x8* ap = reinterpret_cast<const s16x8*>(
        ws + (size_t)(b * MM + arow) * HW);  // 128 16B-chunks per row

    // A-fragments: asm loads pinned in the vmcnt FIFO; af[s&3][ch] static-
    // indexed after full unroll (rule #20).
    s16x8 af[ND][4];
    auto load_af = [&](int s) {
        const int pb = s & (ND - 1);
#pragma unroll
        for (int ch = 0; ch < 4; ++ch) {
            const s16x8* a = ap + s * 16 + ch * 4 + q;
            asm volatile("global_load_dwordx4 %0, %1, off"
                         : "=&v"(af[pb][ch]) : "v"(a) : "memory");
        }
    };

    f32x4 acc = {0.f, 0.f, 0.f, 0.f};

    auto compute = [&](int s) {
        const int nb = s & (ND - 1);
#pragma unroll
        for (int ch = 0; ch < 4; ++ch) {              // four K=32 chunks
            const int S0 = ch * 8 + 2 * q;            // 16B slot of lo half
            f32x4 blo = *reinterpret_cast<const f32x4*>(
                &fsh[nb][brow][(S0 ^ r) * 4]);
            f32x4 bhi = *reinterpret_cast<const f32x4*>(
                &fsh[nb][brow][((S0 + 1) ^ r) * 4]);
            acc = __builtin_amdgcn_mfma_f32_16x16x32_bf16(
                      af[nb][ch], cvt8(blo, bhi), acc, 0, 0, 0);
        }
    };

    // ---- prologue: pairs 0,1,2 in flight (24 VMEM ops/lane) ----
    load_af(0); stage(0);
    load_af(1); stage(1);
    load_af(2); stage(2);

    // ---- steady state: vmcnt retires exactly one pair; ONE barrier/iter;
    //      sched_barrier(0) fences reg-only MFMA hoisting (rule #18) ----
#pragma unroll
    for (int s = 0; s < NSTF; ++s) {
        const int rem = NSTF - 1 - s;        // younger pairs outstanding
        if (rem >= 2)      asm volatile("s_waitcnt vmcnt(16)" ::: "memory");
        else if (rem == 1) asm volatile("s_waitcnt vmcnt(8)"  ::: "memory");
        else               asm volatile("s_waitcnt vmcnt(0)"  ::: "memory");
        __builtin_amdgcn_sched_barrier(0);
        __builtin_amdgcn_s_barrier();
        if (s + 3 < NSTF) { load_af(s + 3); stage(s + 3); }
        compute(s);
    }

    // ---- epilogue: D[reg] -> out0[b][mt*16+4q+reg][cbase + c2*16 + r] ----
    const float sc = 1.0f / (float)HW;
    float* p = out0 + (size_t)(b * MM) * CC + cbase + c2 * 16;
#pragma unroll
    for (int reg = 0; reg < 4; ++reg)
        p[(size_t)(mt * 16 + 4 * q + reg) * CC + r] = acc[reg] * sc;
}

extern "C" void kernel_launch(void* const* d_in, const int* in_sizes, int n_in,
                              void* d_out, int out_size, void* d_ws, size_t ws_size,
                              hipStream_t stream)
{
    const float* feat = (const float*)d_in[0];   // [16,1024,32,32]
    const float* raw  = (const float*)d_in[1];   // [16,32,32,32]
    float* out0 = (float*)d_out;                           // [16,32,1024]
    float* out1 = out0 + (size_t)BB * MM * HW;             // [16,32,32,32]
    unsigned short* att_bf = (unsigned short*)d_ws;        // 1 MB of >=8MB ws

    sigmoid_kernel<<<256, 256, 0, stream>>>(raw, out1, att_bf);
    bap_mfma<<<512, 256, 0, stream>>>(feat, att_bf, out0);
}